// Round 7
// baseline (171.720 us; speedup 1.0000x reference)
//
#include <hip/hip_runtime.h>
#include <hip/hip_bf16.h>

// B=8, T=1024, DIM=512, H=8, DK=64, L=32, DH=512, DOUT=512
// qkvb (bf16) layout: [1536][8192], rows {q:0..511,k:512..1023,v:1024..1535}, col = b*1024+t.

typedef short bf16x8 __attribute__((ext_vector_type(8)));
typedef float f32x4 __attribute__((ext_vector_type(4)));

static __device__ __forceinline__ unsigned short f2bf(float f) {
  __hip_bfloat16 h = __float2bfloat16(f);
  return *reinterpret_cast<unsigned short*>(&h);
}
static __device__ __forceinline__ float bf2f(unsigned short u) {
  union { unsigned int i; float f; } c; c.i = ((unsigned int)u) << 16;
  return c.f;
}
static __device__ __forceinline__ void gl_lds16(const unsigned short* g, unsigned short* l) {
  __builtin_amdgcn_global_load_lds((const __attribute__((address_space(1))) unsigned int*)g,
                                   (__attribute__((address_space(3))) unsigned int*)l,
                                   16, 0, 0);
}

// ---------------- prep: cast x/Wqkv/Wout -> bf16  +  PsumT  +  zero S ----------------
__global__ __launch_bounds__(256) void prep(const float* __restrict__ x,
                                            const float* __restrict__ wqkv,
                                            const float* __restrict__ wout,
                                            const float* __restrict__ relpos,
                                            unsigned short* __restrict__ xb,
                                            unsigned short* __restrict__ wqkvb,
                                            unsigned short* __restrict__ woutb,
                                            float* __restrict__ PsumT,
                                            float* __restrict__ S) {
  const int bx = blockIdx.x;
  if (bx < 5120) {
    int j = bx * 256 + threadIdx.x;   // float4 idx: x 1048576 | wqkv 196608 | wout 65536
    const float* src; unsigned short* dst;
    if (j < 1048576) { src = x; dst = xb; }
    else if (j < 1245184) { j -= 1048576; src = wqkv; dst = wqkvb; }
    else { j -= 1245184; src = wout; dst = woutb; }
    float4 v = ((const float4*)src)[j];
    ushort4 o = {f2bf(v.x), f2bf(v.y), f2bf(v.z), f2bf(v.w)};
    ((ushort4*)dst)[j] = o;
  } else if (bx < 5376) {
    const int idx = bx - 5120;            // 256 blocks: d = idx>>2, t-chunk = idx&3
    const int d = idx >> 2;
    const int t = (idx & 3) * 256 + threadIdx.x;
    float acc = 0.f;
    for (int j = 0; j < 63; ++j) {
      int i = t + j - 31;
      float v = relpos[j * 64 + d];
      if (i >= 0 && i < 1024) acc += v;
    }
    PsumT[d * 1024 + t] = acc;
  } else {
    const int idx = (bx - 5376) * 256 + threadIdx.x;   // 16384 float4s = 65536 floats
    ((float4*)S)[idx] = (float4){0.f, 0.f, 0.f, 0.f};
  }
}

// ---------------- BK=64 m97-style bf16 MFMA GEMM NT (128x128 tile) ----------------
__global__ __launch_bounds__(256) void gemm_qkv(const unsigned short* __restrict__ A,
                                                const unsigned short* __restrict__ B,
                                                unsigned short* __restrict__ C) {
  __shared__ alignas(16) unsigned short As[8192];
  __shared__ alignas(16) unsigned short Bs[8192];
  const int tid = threadIdx.x;
  const int wave = tid >> 6, lane = tid & 63;
  const int bm = blockIdx.y * 128, bn = blockIdx.x * 128;
  const int wm = (wave >> 1) * 64, wn = (wave & 1) * 64;
  const int fr = lane & 15, cq = lane >> 4;
  const unsigned short* srcA[4];
  const unsigned short* srcB[4];
#pragma unroll
  for (int j = 0; j < 4; ++j) {
    const int s = tid + j * 256;
    const int row = s >> 3, cp = s & 7;
    const int c = cp ^ (row & 7);
    srcA[j] = A + (size_t)(bm + row) * 512 + c * 8;
    srcB[j] = B + (size_t)(bn + row) * 512 + c * 8;
  }
  int offA[4][2], offB[4][2];
#pragma unroll
  for (int i = 0; i < 4; ++i)
#pragma unroll
    for (int ks = 0; ks < 2; ++ks) {
      int ra = wm + i * 16 + fr;
      offA[i][ks] = (ra * 8 + ((ks * 4 + cq) ^ (ra & 7))) * 8;
      int rb = wn + i * 16 + fr;
      offB[i][ks] = (rb * 8 + ((ks * 4 + cq) ^ (rb & 7))) * 8;
    }
  f32x4 acc[4][4];
#pragma unroll
  for (int i = 0; i < 4; ++i)
#pragma unroll
    for (int j = 0; j < 4; ++j) acc[i][j] = (f32x4){0.f, 0.f, 0.f, 0.f};
  for (int k0 = 0; k0 < 512; k0 += 64) {
    __syncthreads();
#pragma unroll
    for (int j = 0; j < 4; ++j) {
      gl_lds16(srcA[j] + k0, As + (wave * 64 + j * 256) * 8);
      gl_lds16(srcB[j] + k0, Bs + (wave * 64 + j * 256) * 8);
    }
    __builtin_amdgcn_s_waitcnt(0);
    __syncthreads();
#pragma unroll
    for (int ks = 0; ks < 2; ++ks) {
      bf16x8 af[4], bq[4];
#pragma unroll
      for (int mi = 0; mi < 4; ++mi) af[mi] = *(const bf16x8*)(As + offA[mi][ks]);
#pragma unroll
      for (int nj = 0; nj < 4; ++nj) bq[nj] = *(const bf16x8*)(Bs + offB[nj][ks]);
#pragma unroll
      for (int mi = 0; mi < 4; ++mi)
#pragma unroll
        for (int nj = 0; nj < 4; ++nj)
          acc[mi][nj] = __builtin_amdgcn_mfma_f32_16x16x32_bf16(af[mi], bq[nj], acc[mi][nj], 0, 0, 0);
    }
  }
#pragma unroll
  for (int mi = 0; mi < 4; ++mi) {
    const int row0 = bm + wm + mi * 16 + (lane >> 4) * 4;
#pragma unroll
    for (int nj = 0; nj < 4; ++nj) {
      const int col = bn + wn + nj * 16 + fr;
#pragma unroll
      for (int rr = 0; rr < 4; ++rr)
        C[(size_t)(row0 + rr) * 8192 + col] = f2bf(acc[mi][nj][rr]);
    }
  }
}

__global__ __launch_bounds__(256) void gemm_out(const unsigned short* __restrict__ A,
                                                const unsigned short* __restrict__ B,
                                                const float* __restrict__ bias,
                                                float* __restrict__ out) {
  __shared__ alignas(16) unsigned short As[8192];
  __shared__ alignas(16) unsigned short Bs[8192];
  const int tid = threadIdx.x;
  const int wave = tid >> 6, lane = tid & 63;
  const int bm = blockIdx.y * 128, bn = blockIdx.x * 128;
  const int wm = (wave >> 1) * 64, wn = (wave & 1) * 64;
  const int fr = lane & 15, cq = lane >> 4;
  const unsigned short* srcA[4];
  const unsigned short* srcB[4];
#pragma unroll
  for (int j = 0; j < 4; ++j) {
    const int s = tid + j * 256;
    const int row = s >> 3, cp = s & 7;
    const int c = cp ^ (row & 7);
    srcA[j] = A + (size_t)(bm + row) * 512 + c * 8;
    srcB[j] = B + (size_t)(bn + row) * 512 + c * 8;
  }
  int offA[4][2], offB[4][2];
#pragma unroll
  for (int i = 0; i < 4; ++i)
#pragma unroll
    for (int ks = 0; ks < 2; ++ks) {
      int ra = wm + i * 16 + fr;
      offA[i][ks] = (ra * 8 + ((ks * 4 + cq) ^ (ra & 7))) * 8;
      int rb = wn + i * 16 + fr;
      offB[i][ks] = (rb * 8 + ((ks * 4 + cq) ^ (rb & 7))) * 8;
    }
  f32x4 acc[4][4];
#pragma unroll
  for (int i = 0; i < 4; ++i)
#pragma unroll
    for (int j = 0; j < 4; ++j) acc[i][j] = (f32x4){0.f, 0.f, 0.f, 0.f};
  for (int k0 = 0; k0 < 512; k0 += 64) {
    __syncthreads();
#pragma unroll
    for (int j = 0; j < 4; ++j) {
      gl_lds16(srcA[j] + k0, As + (wave * 64 + j * 256) * 8);
      gl_lds16(srcB[j] + k0, Bs + (wave * 64 + j * 256) * 8);
    }
    __builtin_amdgcn_s_waitcnt(0);
    __syncthreads();
#pragma unroll
    for (int ks = 0; ks < 2; ++ks) {
      bf16x8 af[4], bq[4];
#pragma unroll
      for (int mi = 0; mi < 4; ++mi) af[mi] = *(const bf16x8*)(As + offA[mi][ks]);
#pragma unroll
      for (int nj = 0; nj < 4; ++nj) bq[nj] = *(const bf16x8*)(Bs + offB[nj][ks]);
#pragma unroll
      for (int mi = 0; mi < 4; ++mi)
#pragma unroll
        for (int nj = 0; nj < 4; ++nj)
          acc[mi][nj] = __builtin_amdgcn_mfma_f32_16x16x32_bf16(af[mi], bq[nj], acc[mi][nj], 0, 0, 0);
    }
  }
#pragma unroll
  for (int mi = 0; mi < 4; ++mi) {
    const int row0 = bm + wm + mi * 16 + (lane >> 4) * 4;
#pragma unroll
    for (int nj = 0; nj < 4; ++nj) {
      const int col = bn + wn + nj * 16 + fr;   // g = b*1024 + t
      const int b = col >> 10, t = col & 1023;
#pragma unroll
      for (int rr = 0; rr < 4; ++rr)
        out[(size_t)b * 524288 + (size_t)(row0 + rr) * 1024 + t] = acc[mi][nj][rr] + bias[row0 + rr];
    }
  }
}

// ---------------- ctx_s: per (n, d-quarter): in-block lse + p + ctx direct + S atomics ----
// grid 256 blocks, swizzled so the 4 blocks of one n are 8 apart (same XCD under RR).
__global__ __launch_bounds__(256) void ctx_s_kernel(const unsigned short* __restrict__ qkv,
                                                    const float* __restrict__ PsumT,
                                                    float* __restrict__ S,
                                                    float* __restrict__ ctx) {
  const int bx = blockIdx.x;
  const int n = (bx & 7) | ((bx >> 5) << 3);
  const int dq = (bx >> 3) & 3;
  const int b = n >> 3, h = n & 7;
  const int tid = threadIdx.x, wave = tid >> 6, lane = tid & 63;
  const int quad = lane >> 4, fr = lane & 15;
  __shared__ alignas(16) unsigned short kp[16][1028];
  __shared__ float ls[16];
  __shared__ float ctx_l[16][68];
  // P1: load k rows [dq*16, dq*16+16), full t -> LDS
  const unsigned short* kbase = qkv + (size_t)(512 + h * 64 + dq * 16) * 8192 + b * 1024;
#pragma unroll
  for (int it = 0; it < 8; ++it) {
    const int idx = it * 2048 + tid * 8;
    const int row = idx >> 10, col = idx & 1023;
    bf16x8 val = *(const bf16x8*)(kbase + (size_t)row * 8192 + col);
    *(bf16x8*)&kp[row][col] = val;
  }
  // P2 (global-only): partial S for this block's 16 d-rows, atomic into S
  {
    const unsigned short* qbase = qkv + (size_t)(h * 64 + dq * 16) * 8192 + b * 1024
                                  + wave * 256 + lane * 4;
    const float* pb = PsumT + (dq * 16) * 1024 + wave * 256 + lane * 4;
    float s0 = 0.f, s1 = 0.f, s2 = 0.f, s3 = 0.f;
#pragma unroll
    for (int d = 0; d < 16; ++d) {
      ushort4 qv = *(const ushort4*)(qbase + (size_t)d * 8192);
      float4 pv = *(const float4*)(pb + d * 1024);
      s0 = fmaf(bf2f(qv.x), pv.x, s0);
      s1 = fmaf(bf2f(qv.y), pv.y, s1);
      s2 = fmaf(bf2f(qv.z), pv.z, s2);
      s3 = fmaf(bf2f(qv.w), pv.w, s3);
    }
    float* sp = S + (size_t)n * 1024 + wave * 256 + lane * 4;
    atomicAdd(sp + 0, s0);
    atomicAdd(sp + 1, s1);
    atomicAdd(sp + 2, s2);
    atomicAdd(sp + 3, s3);
  }
  __syncthreads();
  // P3: lse per row (wave w handles rows w*4..w*4+3)
#pragma unroll
  for (int r4 = 0; r4 < 4; ++r4) {
    const int row = wave * 4 + r4;
    bf16x8 v0 = *(const bf16x8*)&kp[row][lane * 16];
    bf16x8 v1 = *(const bf16x8*)&kp[row][lane * 16 + 8];
    float fv[16];
#pragma unroll
    for (int j = 0; j < 8; ++j) {
      fv[j] = bf2f((unsigned short)v0[j]);
      fv[8 + j] = bf2f((unsigned short)v1[j]);
    }
    float m = fv[0];
#pragma unroll
    for (int j = 1; j < 16; ++j) m = fmaxf(m, fv[j]);
#pragma unroll
    for (int off = 32; off; off >>= 1) m = fmaxf(m, __shfl_xor(m, off));
    float s = 0.f;
#pragma unroll
    for (int j = 0; j < 16; ++j) s += __expf(fv[j] - m);
#pragma unroll
    for (int off = 32; off; off >>= 1) s += __shfl_xor(s, off);
    if (lane == 0) ls[row] = m + __logf(s);
  }
  __syncthreads();
  // P4: p = exp(k - lse) in place (bf16)
#pragma unroll
  for (int it = 0; it < 8; ++it) {
    const int idx = it * 2048 + tid * 8;
    const int row = idx >> 10, col = idx & 1023;
    const float lv = ls[row];
    bf16x8 kv = *(bf16x8*)&kp[row][col];
    bf16x8 pv;
#pragma unroll
    for (int j = 0; j < 8; ++j)
      pv[j] = (short)f2bf(__expf(bf2f((unsigned short)kv[j]) - lv));
    *(bf16x8*)&kp[row][col] = pv;
  }
  __syncthreads();
  // P5: ctx MFMA: A = p (LDS), B = v (global), K = 256 t per wave
  f32x4 acc[4];
#pragma unroll
  for (int et = 0; et < 4; ++et) acc[et] = (f32x4){0.f, 0.f, 0.f, 0.f};
  const unsigned short* vbase = qkv + (size_t)(1024 + h * 64) * 8192 + b * 1024 + wave * 256;
#pragma unroll
  for (int ks = 0; ks < 8; ++ks) {
    const int tb = wave * 256 + ks * 32 + quad * 8;
    bf16x8 aF = *(const bf16x8*)&kp[fr][tb];
#pragma unroll
    for (int et = 0; et < 4; ++et) {
      bf16x8 bF = *(const bf16x8*)(vbase + (size_t)(et * 16 + fr) * 8192 + ks * 32 + quad * 8);
      acc[et] = __builtin_amdgcn_mfma_f32_16x16x32_bf16(aF, bF, acc[et], 0, 0, 0);
    }
  }
  // cross-wave reduce
#pragma unroll
  for (int w2 = 0; w2 < 4; ++w2) {
    if (wave == w2) {
#pragma unroll
      for (int et = 0; et < 4; ++et)
#pragma unroll
        for (int rr = 0; rr < 4; ++rr) {
          const int rd = quad * 4 + rr, ce = et * 16 + fr;
          if (w2 == 0) ctx_l[rd][ce] = acc[et][rr];
          else ctx_l[rd][ce] += acc[et][rr];
        }
    }
    __syncthreads();
  }
  // P6: write ctx slice
  const int idx = tid * 4;
  const int rd = idx >> 6, ce = idx & 63;
  float4 val = *(const float4*)&ctx_l[rd][ce];
  *(float4*)(ctx + (size_t)n * 4096 + (size_t)(dq * 16 + rd) * 64 + ce) = val;
}

// ---------------- bn_chan: per-channel BN stats + final (one block per e) ----------------
__global__ __launch_bounds__(256) void bn_chan(const unsigned short* __restrict__ qkv,
                                               const float* __restrict__ S,
                                               const float* __restrict__ gamma,
                                               const float* __restrict__ beta,
                                               float* __restrict__ scale,
                                               float* __restrict__ shift) {
  const int e = blockIdx.x, tid = threadIdx.x;
  float a1 = 0.f, a2 = 0.f;
  for (int n = 0; n < 64; ++n) {
    const int b = n >> 3, h = n & 7;
    ushort4 vv = *(const ushort4*)(qkv + (size_t)(1024 + h * 64 + e) * 8192 + b * 1024 + tid * 4);
    float4 sv = *(const float4*)(S + (size_t)n * 1024 + tid * 4);
    float v0 = bf2f(vv.x) * sv.x;
    float v1 = bf2f(vv.y) * sv.y;
    float v2 = bf2f(vv.z) * sv.z;
    float v3 = bf2f(vv.w) * sv.w;
    a1 += v0 + v1 + v2 + v3;
    a2 = fmaf(v0, v0, a2); a2 = fmaf(v1, v1, a2);
    a2 = fmaf(v2, v2, a2); a2 = fmaf(v3, v3, a2);
  }
#pragma unroll
  for (int off = 32; off; off >>= 1) {
    a1 += __shfl_down(a1, off);
    a2 += __shfl_down(a2, off);
  }
  __shared__ float r1[4], r2[4];
  const int w = tid >> 6, lane = tid & 63;
  if (lane == 0) { r1[w] = a1; r2[w] = a2; }
  __syncthreads();
  if (tid == 0) {
    float s1 = r1[0] + r1[1] + r1[2] + r1[3];
    float s2 = r2[0] + r2[1] + r2[2] + r2[3];
    const float cnt = 65536.0f;
    float mu = s1 / cnt;
    float var = s2 / cnt - mu * mu;
    float sc = gamma[e] * rsqrtf(var + 1e-5f);
    scale[e] = sc;
    shift[e] = beta[e] - mu * sc;
  }
}

// ---------------- fused content + BN-combine + transpose -> outT bf16 ----------------
__global__ __launch_bounds__(256) void content_out_t(const unsigned short* __restrict__ qkv,
                                                     const float* __restrict__ ctx,
                                                     const float* __restrict__ S,
                                                     const float* __restrict__ scale,
                                                     const float* __restrict__ shift,
                                                     unsigned short* __restrict__ outT) {
  const int chunk = blockIdx.x, n = blockIdx.y;   // grid (16, 64)
  const int b = n >> 3, h = n & 7;
  const int t0 = chunk * 64;
  __shared__ float cs[4096];
  __shared__ alignas(16) unsigned short T[64][72];
  const float* cp = ctx + (size_t)n * 4096;
  for (int i = threadIdx.x * 4; i < 4096; i += 1024)
    *(float4*)&cs[i] = *(const float4*)&cp[i];
  __syncthreads();
  const int tid = threadIdx.x;
  const int e0 = (tid & 15) * 4;
  const int tq = (tid >> 4) * 4;
  const unsigned short* qbase = qkv + (size_t)(h * 64) * 8192 + b * 1024 + t0 + tq;
  float acc[4][4] = {{0.f}};
  for (int d = 0; d < 64; ++d) {
    float4 cv = *(const float4*)&cs[d * 64 + e0];
    ushort4 qu = *(const ushort4*)(qbase + (size_t)d * 8192);
    float qa[4] = {bf2f(qu.x), bf2f(qu.y), bf2f(qu.z), bf2f(qu.w)};
    float ca[4] = {cv.x, cv.y, cv.z, cv.w};
#pragma unroll
    for (int a = 0; a < 4; ++a)
#pragma unroll
      for (int c = 0; c < 4; ++c)
        acc[a][c] = fmaf(ca[a], qa[c], acc[a][c]);
  }
  float4 svv = *(const float4*)(S + (size_t)n * 1024 + t0 + tq);
  float sa[4] = {svv.x, svv.y, svv.z, svv.w};
  float4 scv = *(const float4*)(scale + e0);
  float4 shv = *(const float4*)(shift + e0);
  float sc[4] = {scv.x, scv.y, scv.z, scv.w};
  float sh[4] = {shv.x, shv.y, shv.z, shv.w};
#pragma unroll
  for (int a = 0; a < 4; ++a) {
    ushort4 vu = *(const ushort4*)(qkv + (size_t)(1024 + h * 64 + e0 + a) * 8192 + b * 1024 + t0 + tq);
    float va[4] = {bf2f(vu.x), bf2f(vu.y), bf2f(vu.z), bf2f(vu.w)};
#pragma unroll
    for (int c = 0; c < 4; ++c)
      T[tq + c][e0 + a] = f2bf(fmaf(va[c] * sa[c], sc[a], acc[a][c] + sh[a]));
  }
  __syncthreads();
  const int tl = tid >> 2, dq = (tid & 3) * 16;
  uint4 r0 = *(uint4*)&T[tl][dq];
  uint4 r1 = *(uint4*)&T[tl][dq + 8];
  unsigned short* op = outT + ((size_t)(b * 1024 + t0 + tl)) * 512 + h * 64 + dq;
  *(uint4*)op = r0;
  *(uint4*)(op + 8) = r1;
}

extern "C" void kernel_launch(void* const* d_in, const int* in_sizes, int n_in,
                              void* d_out, int out_size, void* d_ws, size_t ws_size,
                              hipStream_t stream) {
  const float* x       = (const float*)d_in[0];
  const float* Wqkv    = (const float*)d_in[1];
  const float* Wout    = (const float*)d_in[2];
  const float* bout    = (const float*)d_in[3];
  const float* relpos  = (const float*)d_in[4];
  const float* gamma   = (const float*)d_in[5];
  const float* beta    = (const float*)d_in[6];
  float* out = (float*)d_out;

  float* ws = (float*)d_ws;
  unsigned short* qkvb  = (unsigned short*)ws;             // 1536*8192 bf16
  float* p = ws + 6291456;
  unsigned short* xb    = (unsigned short*)p;  p += 2097152;   // 8192x512 bf16
  unsigned short* wqkvb = (unsigned short*)p;  p += 393216;    // 1536x512 bf16
  unsigned short* woutb = (unsigned short*)p;  p += 131072;    // 512x512 bf16
  float* ctx      = p;  p += 262144;                           // 64x64x64 fp32
  float* PsumT    = p;  p += 65536;
  float* S        = p;  p += 65536;
  float* scale    = p;  p += 64;
  float* shift    = p;  p += 64;
  unsigned short* outT = (unsigned short*)p;                   // 8192x512 bf16

  // 0. prep: cast inputs + PsumT + zero S
  prep<<<5440, 256, 0, stream>>>(x, Wqkv, Wout, relpos, xb, wqkvb, woutb, PsumT, S);
  // 1. qkv (bf16) = Wqkv @ x^T, BK=64 global_load_lds GEMM
  gemm_qkv<<<dim3(64, 12), 256, 0, stream>>>(wqkvb, xb, qkvb);
  // 2. fused lse + softmax-apply + ctx (direct) + S partial-atomics
  ctx_s_kernel<<<256, 256, 0, stream>>>(qkvb, PsumT, S, ctx);
  // 3. BN stats+final per channel
  bn_chan<<<64, 256, 0, stream>>>(qkvb, S, gamma, beta, scale, shift);
  // 4. fused content + BN-combine + transpose
  content_out_t<<<dim3(16, 64), 256, 0, stream>>>(qkvb, ctx, S, scale, shift, outT);
  // 5. final GEMM: out = Wout @ comb + bout
  gemm_out<<<dim3(64, 4), 256, 0, stream>>>(woutb, outT, bout, out);
}

// Round 8
// 164.809 us; speedup vs baseline: 1.0419x; 1.0419x over previous
//
#include <hip/hip_runtime.h>
#include <hip/hip_bf16.h>

// B=8, T=1024, DIM=512, H=8, DK=64, L=32, DH=512, DOUT=512
// qkvb (bf16) layout: [1536][8192], rows {q:0..511,k:512..1023,v:1024..1535}, col = b*1024+t.

typedef short bf16x8 __attribute__((ext_vector_type(8)));
typedef float f32x4 __attribute__((ext_vector_type(4)));

static __device__ __forceinline__ unsigned short f2bf(float f) {
  __hip_bfloat16 h = __float2bfloat16(f);
  return *reinterpret_cast<unsigned short*>(&h);
}
static __device__ __forceinline__ float bf2f(unsigned short u) {
  union { unsigned int i; float f; } c; c.i = ((unsigned int)u) << 16;
  return c.f;
}
static __device__ __forceinline__ void gl_lds16(const unsigned short* g, unsigned short* l) {
  __builtin_amdgcn_global_load_lds((const __attribute__((address_space(1))) unsigned int*)g,
                                   (__attribute__((address_space(3))) unsigned int*)l,
                                   16, 0, 0);
}

// ---------------- prep: cast x/Wqkv/Wout -> bf16  +  PsumT ----------------
__global__ __launch_bounds__(256) void prep(const float* __restrict__ x,
                                            const float* __restrict__ wqkv,
                                            const float* __restrict__ wout,
                                            const float* __restrict__ relpos,
                                            unsigned short* __restrict__ xb,
                                            unsigned short* __restrict__ wqkvb,
                                            unsigned short* __restrict__ woutb,
                                            float* __restrict__ PsumT) {
  const int bx = blockIdx.x;
  if (bx < 5120) {
    int j = bx * 256 + threadIdx.x;   // float4 idx: x 1048576 | wqkv 196608 | wout 65536
    const float* src; unsigned short* dst;
    if (j < 1048576) { src = x; dst = xb; }
    else if (j < 1245184) { j -= 1048576; src = wqkv; dst = wqkvb; }
    else { j -= 1245184; src = wout; dst = woutb; }
    float4 v = ((const float4*)src)[j];
    ushort4 o = {f2bf(v.x), f2bf(v.y), f2bf(v.z), f2bf(v.w)};
    ((ushort4*)dst)[j] = o;
  } else {
    const int idx = bx - 5120;            // 256 blocks: d = idx>>2, t-chunk = idx&3
    const int d = idx >> 2;
    const int t = (idx & 3) * 256 + threadIdx.x;
    float acc = 0.f;
    for (int j = 0; j < 63; ++j) {
      int i = t + j - 31;
      float v = relpos[j * 64 + d];
      if (i >= 0 && i < 1024) acc += v;
    }
    PsumT[d * 1024 + t] = acc;
  }
}

// ---------------- BK=64 m97-style bf16 MFMA GEMM NT (128x128 tile) ----------------
__global__ __launch_bounds__(256) void gemm_qkv(const unsigned short* __restrict__ A,
                                                const unsigned short* __restrict__ B,
                                                unsigned short* __restrict__ C) {
  __shared__ alignas(16) unsigned short As[8192];
  __shared__ alignas(16) unsigned short Bs[8192];
  const int tid = threadIdx.x;
  const int wave = tid >> 6, lane = tid & 63;
  const int bm = blockIdx.y * 128, bn = blockIdx.x * 128;
  const int wm = (wave >> 1) * 64, wn = (wave & 1) * 64;
  const int fr = lane & 15, cq = lane >> 4;
  const unsigned short* srcA[4];
  const unsigned short* srcB[4];
#pragma unroll
  for (int j = 0; j < 4; ++j) {
    const int s = tid + j * 256;
    const int row = s >> 3, cp = s & 7;
    const int c = cp ^ (row & 7);
    srcA[j] = A + (size_t)(bm + row) * 512 + c * 8;
    srcB[j] = B + (size_t)(bn + row) * 512 + c * 8;
  }
  int offA[4][2], offB[4][2];
#pragma unroll
  for (int i = 0; i < 4; ++i)
#pragma unroll
    for (int ks = 0; ks < 2; ++ks) {
      int ra = wm + i * 16 + fr;
      offA[i][ks] = (ra * 8 + ((ks * 4 + cq) ^ (ra & 7))) * 8;
      int rb = wn + i * 16 + fr;
      offB[i][ks] = (rb * 8 + ((ks * 4 + cq) ^ (rb & 7))) * 8;
    }
  f32x4 acc[4][4];
#pragma unroll
  for (int i = 0; i < 4; ++i)
#pragma unroll
    for (int j = 0; j < 4; ++j) acc[i][j] = (f32x4){0.f, 0.f, 0.f, 0.f};
  for (int k0 = 0; k0 < 512; k0 += 64) {
    __syncthreads();
#pragma unroll
    for (int j = 0; j < 4; ++j) {
      gl_lds16(srcA[j] + k0, As + (wave * 64 + j * 256) * 8);
      gl_lds16(srcB[j] + k0, Bs + (wave * 64 + j * 256) * 8);
    }
    __builtin_amdgcn_s_waitcnt(0);
    __syncthreads();
#pragma unroll
    for (int ks = 0; ks < 2; ++ks) {
      bf16x8 af[4], bq[4];
#pragma unroll
      for (int mi = 0; mi < 4; ++mi) af[mi] = *(const bf16x8*)(As + offA[mi][ks]);
#pragma unroll
      for (int nj = 0; nj < 4; ++nj) bq[nj] = *(const bf16x8*)(Bs + offB[nj][ks]);
#pragma unroll
      for (int mi = 0; mi < 4; ++mi)
#pragma unroll
        for (int nj = 0; nj < 4; ++nj)
          acc[mi][nj] = __builtin_amdgcn_mfma_f32_16x16x32_bf16(af[mi], bq[nj], acc[mi][nj], 0, 0, 0);
    }
  }
#pragma unroll
  for (int mi = 0; mi < 4; ++mi) {
    const int row0 = bm + wm + mi * 16 + (lane >> 4) * 4;
#pragma unroll
    for (int nj = 0; nj < 4; ++nj) {
      const int col = bn + wn + nj * 16 + fr;
#pragma unroll
      for (int rr = 0; rr < 4; ++rr)
        C[(size_t)(row0 + rr) * 8192 + col] = f2bf(acc[mi][nj][rr]);
    }
  }
}

__global__ __launch_bounds__(256) void gemm_out(const unsigned short* __restrict__ A,
                                                const unsigned short* __restrict__ B,
                                                const float* __restrict__ bias,
                                                float* __restrict__ out) {
  __shared__ alignas(16) unsigned short As[8192];
  __shared__ alignas(16) unsigned short Bs[8192];
  const int tid = threadIdx.x;
  const int wave = tid >> 6, lane = tid & 63;
  const int bm = blockIdx.y * 128, bn = blockIdx.x * 128;
  const int wm = (wave >> 1) * 64, wn = (wave & 1) * 64;
  const int fr = lane & 15, cq = lane >> 4;
  const unsigned short* srcA[4];
  const unsigned short* srcB[4];
#pragma unroll
  for (int j = 0; j < 4; ++j) {
    const int s = tid + j * 256;
    const int row = s >> 3, cp = s & 7;
    const int c = cp ^ (row & 7);
    srcA[j] = A + (size_t)(bm + row) * 512 + c * 8;
    srcB[j] = B + (size_t)(bn + row) * 512 + c * 8;
  }
  int offA[4][2], offB[4][2];
#pragma unroll
  for (int i = 0; i < 4; ++i)
#pragma unroll
    for (int ks = 0; ks < 2; ++ks) {
      int ra = wm + i * 16 + fr;
      offA[i][ks] = (ra * 8 + ((ks * 4 + cq) ^ (ra & 7))) * 8;
      int rb = wn + i * 16 + fr;
      offB[i][ks] = (rb * 8 + ((ks * 4 + cq) ^ (rb & 7))) * 8;
    }
  f32x4 acc[4][4];
#pragma unroll
  for (int i = 0; i < 4; ++i)
#pragma unroll
    for (int j = 0; j < 4; ++j) acc[i][j] = (f32x4){0.f, 0.f, 0.f, 0.f};
  for (int k0 = 0; k0 < 512; k0 += 64) {
    __syncthreads();
#pragma unroll
    for (int j = 0; j < 4; ++j) {
      gl_lds16(srcA[j] + k0, As + (wave * 64 + j * 256) * 8);
      gl_lds16(srcB[j] + k0, Bs + (wave * 64 + j * 256) * 8);
    }
    __builtin_amdgcn_s_waitcnt(0);
    __syncthreads();
#pragma unroll
    for (int ks = 0; ks < 2; ++ks) {
      bf16x8 af[4], bq[4];
#pragma unroll
      for (int mi = 0; mi < 4; ++mi) af[mi] = *(const bf16x8*)(As + offA[mi][ks]);
#pragma unroll
      for (int nj = 0; nj < 4; ++nj) bq[nj] = *(const bf16x8*)(Bs + offB[nj][ks]);
#pragma unroll
      for (int mi = 0; mi < 4; ++mi)
#pragma unroll
        for (int nj = 0; nj < 4; ++nj)
          acc[mi][nj] = __builtin_amdgcn_mfma_f32_16x16x32_bf16(af[mi], bq[nj], acc[mi][nj], 0, 0, 0);
    }
  }
#pragma unroll
  for (int mi = 0; mi < 4; ++mi) {
    const int row0 = bm + wm + mi * 16 + (lane >> 4) * 4;
#pragma unroll
    for (int nj = 0; nj < 4; ++nj) {
      const int col = bn + wn + nj * 16 + fr;   // g = b*1024 + t
      const int b = col >> 10, t = col & 1023;
#pragma unroll
      for (int rr = 0; rr < 4; ++rr)
        out[(size_t)b * 524288 + (size_t)(row0 + rr) * 1024 + t] = acc[mi][nj][rr] + bias[row0 + rr];
    }
  }
}

// ---------------- fused stats: blocks [0,1024) = S+BN partials; [1024,2048) = k logsumexp ----
__global__ __launch_bounds__(256) void stats(const unsigned short* __restrict__ qkv,
                                             const float* __restrict__ PsumT,
                                             float* __restrict__ S,
                                             float* __restrict__ part1,
                                             float* __restrict__ part2,
                                             float* __restrict__ lse) {
  const int bx = blockIdx.x;
  const int tid = threadIdx.x, wave = tid >> 6, lane = tid & 63;
  __shared__ float swave[4][64];
  __shared__ float s_lds[64];
  if (bx < 1024) {
    const int tc = bx & 15, n = bx >> 4;
    const int b = n >> 3, h = n & 7;
    const int t0 = tc * 64;
    const int tg = lane & 7, rg = lane >> 3;
    const unsigned short* qbase = qkv + (size_t)(h * 64) * 8192 + b * 1024 + t0 + tg * 8;
    const float* pbase = PsumT + t0 + tg * 8;
    float acc[8] = {0.f};
#pragma unroll
    for (int i = 0; i < 2; ++i) {
      const int d = wave * 16 + i * 8 + rg;
      bf16x8 qv = *(const bf16x8*)(qbase + (size_t)d * 8192);
      float4 p0 = *(const float4*)(pbase + d * 1024);
      float4 p1 = *(const float4*)(pbase + d * 1024 + 4);
      float p[8] = {p0.x, p0.y, p0.z, p0.w, p1.x, p1.y, p1.z, p1.w};
#pragma unroll
      for (int j = 0; j < 8; ++j) acc[j] = fmaf(bf2f((unsigned short)qv[j]), p[j], acc[j]);
    }
#pragma unroll
    for (int off = 8; off < 64; off <<= 1)
#pragma unroll
      for (int j = 0; j < 8; ++j) acc[j] += __shfl_xor(acc[j], off);
    if (rg == 0) {
#pragma unroll
      for (int j = 0; j < 8; ++j) swave[wave][tg * 8 + j] = acc[j];
    }
    __syncthreads();
    if (tid < 64) {
      float s = swave[0][tid] + swave[1][tid] + swave[2][tid] + swave[3][tid];
      s_lds[tid] = s;
      S[(size_t)n * 1024 + t0 + tid] = s;
    }
    __syncthreads();
    const unsigned short* vbase = qkv + (size_t)(1024 + h * 64) * 8192 + b * 1024 + t0 + tg * 8;
    const int blk = n * 16 + tc;
    float sv[8];
#pragma unroll
    for (int j = 0; j < 8; ++j) sv[j] = s_lds[tg * 8 + j];
#pragma unroll
    for (int i = 0; i < 2; ++i) {
      const int e = wave * 16 + i * 8 + rg;
      bf16x8 vv = *(const bf16x8*)(vbase + (size_t)e * 8192);
      float a1 = 0.f, a2 = 0.f;
#pragma unroll
      for (int j = 0; j < 8; ++j) {
        float val = bf2f((unsigned short)vv[j]) * sv[j];
        a1 += val;
        a2 = fmaf(val, val, a2);
      }
#pragma unroll
      for (int off = 1; off < 8; off <<= 1) {
        a1 += __shfl_xor(a1, off);
        a2 += __shfl_xor(a2, off);
      }
      if (tg == 0) {
        part1[e * 1024 + blk] = a1;
        part2[e * 1024 + blk] = a2;
      }
    }
  } else {
    const int r = (bx - 1024) * 4 + wave;     // 0..4095 = hd*8 + b
    const int hd = r >> 3, b = r & 7;
    const unsigned short* row = qkv + (size_t)(512 + hd) * 8192 + b * 1024 + lane * 16;
    uint4 u0 = *(const uint4*)row;
    uint4 u1 = *(const uint4*)(row + 8);
    const unsigned short* us0 = (const unsigned short*)&u0;
    const unsigned short* us1 = (const unsigned short*)&u1;
    float f[16];
#pragma unroll
    for (int i = 0; i < 8; ++i) { f[i] = bf2f(us0[i]); f[8 + i] = bf2f(us1[i]); }
    float m = f[0];
#pragma unroll
    for (int i = 1; i < 16; ++i) m = fmaxf(m, f[i]);
#pragma unroll
    for (int off = 32; off; off >>= 1) m = fmaxf(m, __shfl_xor(m, off));
    float s = 0.f;
#pragma unroll
    for (int i = 0; i < 16; ++i) s += __expf(f[i] - m);
#pragma unroll
    for (int off = 32; off; off >>= 1) s += __shfl_xor(s, off);
    if (lane == 0) lse[r] = m + __logf(s);
  }
}

// ---------------- ctx_bn: blocks [0,256) context MFMA; [256,320) BN final ----------------
// Safe: this dispatch starts after `stats` completes (part1/part2/lse ready).
__global__ __launch_bounds__(256) void ctx_bn(const unsigned short* __restrict__ qkv,
                                              const float* __restrict__ lse,
                                              float* __restrict__ ctx_part,
                                              const float* __restrict__ part1,
                                              const float* __restrict__ part2,
                                              const float* __restrict__ gamma,
                                              const float* __restrict__ beta,
                                              float* __restrict__ scale,
                                              float* __restrict__ shift) {
  const int bx = blockIdx.x;
  const int tid = threadIdx.x;
  const int wave = tid >> 6, lane = tid & 63;
  __shared__ float ls[64];
  __shared__ float ctx_l[64][68];
  if (bx < 256) {
    const int tc = bx & 3, n = bx >> 2;
    const int b = n >> 3, h = n & 7;
    if (tid < 64) ls[tid] = lse[(h * 64 + tid) * 8 + b];
    __syncthreads();
    const int fr = lane & 15, fk = (lane >> 4) * 8;
    const size_t colbase = (size_t)b * 1024 + tc * 256 + wave * 64;
    const unsigned short* kbase = qkv + (size_t)(512 + h * 64) * 8192 + colbase;
    const unsigned short* vbase = qkv + (size_t)(1024 + h * 64) * 8192 + colbase;
    f32x4 acc[4][4];
#pragma unroll
    for (int i = 0; i < 4; ++i)
#pragma unroll
      for (int j = 0; j < 4; ++j) acc[i][j] = (f32x4){0.f, 0.f, 0.f, 0.f};
#pragma unroll
    for (int ks = 0; ks < 2; ++ks) {
      const int tb = ks * 32 + fk;
      bf16x8 aF[4], bF[4];
#pragma unroll
      for (int dt = 0; dt < 4; ++dt) {
        const int row = dt * 16 + fr;
        bf16x8 kv = *(const bf16x8*)(kbase + (size_t)row * 8192 + tb);
        const float lv = ls[row];
        bf16x8 pv;
#pragma unroll
        for (int j = 0; j < 8; ++j)
          pv[j] = (short)f2bf(__expf(bf2f((unsigned short)kv[j]) - lv));
        aF[dt] = pv;
      }
#pragma unroll
      for (int et = 0; et < 4; ++et)
        bF[et] = *(const bf16x8*)(vbase + (size_t)(et * 16 + fr) * 8192 + tb);
#pragma unroll
      for (int dt = 0; dt < 4; ++dt)
#pragma unroll
        for (int et = 0; et < 4; ++et)
          acc[dt][et] = __builtin_amdgcn_mfma_f32_16x16x32_bf16(aF[dt], bF[et], acc[dt][et], 0, 0, 0);
    }
#pragma unroll
    for (int w = 0; w < 4; ++w) {
      if (wave == w) {
#pragma unroll
        for (int dt = 0; dt < 4; ++dt)
#pragma unroll
          for (int et = 0; et < 4; ++et) {
            const int col = et * 16 + fr;
#pragma unroll
            for (int rr = 0; rr < 4; ++rr) {
              const int rw = dt * 16 + (lane >> 4) * 4 + rr;
              if (w == 0) ctx_l[rw][col] = acc[dt][et][rr];
              else ctx_l[rw][col] += acc[dt][et][rr];
            }
          }
      }
      __syncthreads();
    }
    float* outp = ctx_part + ((size_t)tc * 64 + n) * 4096;
    for (int i = tid * 4; i < 4096; i += 1024) {
      const int rw = i >> 6, cc = i & 63;
      *(float4*)(outp + i) = *(const float4*)&ctx_l[rw][cc];
    }
  } else {
    const int e = bx - 256;
    float a1 = 0.f, a2 = 0.f;
#pragma unroll
    for (int i = 0; i < 4; ++i) {
      a1 += part1[e * 1024 + i * 256 + tid];
      a2 += part2[e * 1024 + i * 256 + tid];
    }
#pragma unroll
    for (int off = 32; off; off >>= 1) {
      a1 += __shfl_down(a1, off);
      a2 += __shfl_down(a2, off);
    }
    if (lane == 0) { ls[wave] = a1; ls[8 + wave] = a2; }
    __syncthreads();
    if (tid == 0) {
      float s1 = ls[0] + ls[1] + ls[2] + ls[3];
      float s2 = ls[8] + ls[9] + ls[10] + ls[11];
      const float cnt = 65536.0f;
      float mu = s1 / cnt;
      float var = s2 / cnt - mu * mu;
      float sc = gamma[e] * rsqrtf(var + 1e-5f);
      scale[e] = sc;
      shift[e] = beta[e] - mu * sc;
    }
  }
}

// ---------------- fused content + BN-combine + transpose -> outT bf16 ----------------
// Sums the 4 ctx_part slices while loading (reduce2's ctx-half folded in).
__global__ __launch_bounds__(256) void content_out_t(const unsigned short* __restrict__ qkv,
                                                     const float* __restrict__ ctx_part,
                                                     const float* __restrict__ S,
                                                     const float* __restrict__ scale,
                                                     const float* __restrict__ shift,
                                                     unsigned short* __restrict__ outT) {
  const int chunk = blockIdx.x, n = blockIdx.y;   // grid (16, 64)
  const int b = n >> 3, h = n & 7;
  const int t0 = chunk * 64;
  __shared__ float cs[4096];
  __shared__ alignas(16) unsigned short T[64][72];
  const float* cp = ctx_part + (size_t)n * 4096;
  for (int i = threadIdx.x * 4; i < 4096; i += 1024) {
    float4 a = *(const float4*)&cp[i];
    float4 b4 = *(const float4*)&cp[262144 + i];
    float4 c4 = *(const float4*)&cp[524288 + i];
    float4 d4 = *(const float4*)&cp[786432 + i];
    float4 s = {a.x + b4.x + c4.x + d4.x, a.y + b4.y + c4.y + d4.y,
                a.z + b4.z + c4.z + d4.z, a.w + b4.w + c4.w + d4.w};
    *(float4*)&cs[i] = s;
  }
  __syncthreads();
  const int tid = threadIdx.x;
  const int e0 = (tid & 15) * 4;
  const int tq = (tid >> 4) * 4;
  const unsigned short* qbase = qkv + (size_t)(h * 64) * 8192 + b * 1024 + t0 + tq;
  float acc[4][4] = {{0.f}};
  for (int d = 0; d < 64; ++d) {
    float4 cv = *(const float4*)&cs[d * 64 + e0];
    ushort4 qu = *(const ushort4*)(qbase + (size_t)d * 8192);
    float qa[4] = {bf2f(qu.x), bf2f(qu.y), bf2f(qu.z), bf2f(qu.w)};
    float ca[4] = {cv.x, cv.y, cv.z, cv.w};
#pragma unroll
    for (int a = 0; a < 4; ++a)
#pragma unroll
      for (int c = 0; c < 4; ++c)
        acc[a][c] = fmaf(ca[a], qa[c], acc[a][c]);
  }
  float4 svv = *(const float4*)(S + (size_t)n * 1024 + t0 + tq);
  float sa[4] = {svv.x, svv.y, svv.z, svv.w};
  float4 scv = *(const float4*)(scale + e0);
  float4 shv = *(const float4*)(shift + e0);
  float sc[4] = {scv.x, scv.y, scv.z, scv.w};
  float sh[4] = {shv.x, shv.y, shv.z, shv.w};
#pragma unroll
  for (int a = 0; a < 4; ++a) {
    ushort4 vu = *(const ushort4*)(qkv + (size_t)(1024 + h * 64 + e0 + a) * 8192 + b * 1024 + t0 + tq);
    float va[4] = {bf2f(vu.x), bf2f(vu.y), bf2f(vu.z), bf2f(vu.w)};
#pragma unroll
    for (int c = 0; c < 4; ++c)
      T[tq + c][e0 + a] = f2bf(fmaf(va[c] * sa[c], sc[a], acc[a][c] + sh[a]));
  }
  __syncthreads();
  const int tl = tid >> 2, dq = (tid & 3) * 16;
  uint4 r0 = *(uint4*)&T[tl][dq];
  uint4 r1 = *(uint4*)&T[tl][dq + 8];
  unsigned short* op = outT + ((size_t)(b * 1024 + t0 + tl)) * 512 + h * 64 + dq;
  *(uint4*)op = r0;
  *(uint4*)(op + 8) = r1;
}

extern "C" void kernel_launch(void* const* d_in, const int* in_sizes, int n_in,
                              void* d_out, int out_size, void* d_ws, size_t ws_size,
                              hipStream_t stream) {
  const float* x       = (const float*)d_in[0];
  const float* Wqkv    = (const float*)d_in[1];
  const float* Wout    = (const float*)d_in[2];
  const float* bout    = (const float*)d_in[3];
  const float* relpos  = (const float*)d_in[4];
  const float* gamma   = (const float*)d_in[5];
  const float* beta    = (const float*)d_in[6];
  float* out = (float*)d_out;

  float* ws = (float*)d_ws;
  unsigned short* qkvb  = (unsigned short*)ws;             // 1536*8192 bf16
  float* p = ws + 6291456;
  unsigned short* xb    = (unsigned short*)p;  p += 2097152;   // 8192x512 bf16
  unsigned short* wqkvb = (unsigned short*)p;  p += 393216;    // 1536x512 bf16
  unsigned short* woutb = (unsigned short*)p;  p += 131072;    // 512x512 bf16
  float* ctx_part = p;  p += 1048576;                          // 4*64*4096
  float* PsumT    = p;  p += 65536;
  float* S        = p;  p += 65536;
  float* lse      = p;  p += 4096;
  float* part1    = p;  p += 65536;
  float* part2    = p;  p += 65536;
  float* scale    = p;  p += 64;
  float* shift    = p;  p += 64;
  unsigned short* outT = (unsigned short*)p;                   // 8192x512 bf16

  // 0. prep: cast inputs + PsumT
  prep<<<5376, 256, 0, stream>>>(x, Wqkv, Wout, relpos, xb, wqkvb, woutb, PsumT);
  // 1. qkv (bf16) = Wqkv @ x^T, BK=64 global_load_lds GEMM
  gemm_qkv<<<dim3(64, 12), 256, 0, stream>>>(wqkvb, xb, qkvb);
  // 2. fused stats: S + BN partials, k-row logsumexp
  stats<<<2048, 256, 0, stream>>>(qkvb, PsumT, S, part1, part2, lse);
  // 3. context MFMA (softmax-apply fused) + BN final (blocks >= 256)
  ctx_bn<<<320, 256, 0, stream>>>(qkvb, lse, ctx_part, part1, part2, gamma, beta, scale, shift);
  // 4. fused content (ctx_part-sum folded in) + BN-combine + transpose
  content_out_t<<<dim3(16, 64), 256, 0, stream>>>(qkvb, ctx_part, S, scale, shift, outT);
  // 5. final GEMM: out = Wout @ comb + bout
  gemm_out<<<dim3(64, 4), 256, 0, stream>>>(woutb, outT, bout, out);
}